// Round 4
// baseline (245.946 us; speedup 1.0000x reference)
//
#include <hip/hip_runtime.h>
#include <stdint.h>

// GCN 2-layer: out = drop(relu(A_hat * (drop(relu((A_hat*X)*W1+b1)) * W2) + b2))
// v5 (measurement round): gathers duplicated (idempotent) to expose their cost via
//     dur delta next round. Embedded wins: single-block scan (scan_a+c merged),
//     eic removed (hist/scatter read raw directly), csr prefetch in gather loop.

#define C_IN 256
#define C_HID 512
#define C_OUT 256

typedef unsigned short ushort_t;
typedef __bf16 bf16x8 __attribute__((ext_vector_type(8)));
typedef float floatx4 __attribute__((ext_vector_type(4)));

typedef __attribute__((address_space(1))) const void g1_void;
typedef __attribute__((address_space(3))) void l3_void;

__device__ __forceinline__ void gll16(const ushort_t* g, ushort_t* l) {
  __builtin_amdgcn_global_load_lds((g1_void*)g, (l3_void*)l, 16, 0, 0);
}

// ---------------- Threefry-2x32 (matches JAX) ----------------
__host__ __device__ __forceinline__ void tf_rounds(unsigned& x0, unsigned& x1,
                                                   unsigned k0, unsigned k1) {
  unsigned k2 = k0 ^ k1 ^ 0x1BD11BDAu;
#define ROT(r) { x0 += x1; x1 = (x1 << r) | (x1 >> (32 - r)); x1 ^= x0; }
  x0 += k0; x1 += k1;
  ROT(13) ROT(15) ROT(26) ROT(6)
  x0 += k1; x1 += k2 + 1u;
  ROT(17) ROT(29) ROT(16) ROT(24)
  x0 += k2; x1 += k0 + 2u;
  ROT(13) ROT(15) ROT(26) ROT(6)
  x0 += k0; x1 += k1 + 3u;
  ROT(17) ROT(29) ROT(16) ROT(24)
  x0 += k1; x1 += k2 + 4u;
  ROT(13) ROT(15) ROT(26) ROT(6)
  x0 += k2; x1 += k0 + 5u;
#undef ROT
}

__device__ __forceinline__ float drop_scale(unsigned j, unsigned k0, unsigned k1) {
  unsigned x0 = 0u, x1 = j;
  tf_rounds(x0, x1, k0, k1);
  unsigned bits = x0 ^ x1;
  float u = __uint_as_float((bits >> 9) | 0x3f800000u) - 1.0f;
  return (u < 0.5f) ? 2.0f : 0.0f;
}

// bf16 helpers (RNE)
__device__ __forceinline__ ushort_t f2bf(float f) {
  unsigned u = __float_as_uint(f);
  unsigned r = (u + 0x7fffu + ((u >> 16) & 1u)) >> 16;
  return (ushort_t)r;
}
__device__ __forceinline__ float bf2f(ushort_t h) {
  return __uint_as_float(((unsigned)h) << 16);
}

// ---------------- fused setup: zero cnt | detect dtype | weight convert ----
__global__ __launch_bounds__(256) void k_setup(const unsigned* __restrict__ raw,
                                               unsigned* __restrict__ flag,
                                               int* __restrict__ cnt, int N, int NB,
                                               const float* __restrict__ W1,
                                               const float* __restrict__ W2,
                                               ushort_t* __restrict__ h1,
                                               ushort_t* __restrict__ l1,
                                               ushort_t* __restrict__ h2,
                                               ushort_t* __restrict__ l2) {
  int b = blockIdx.x, t = threadIdx.x;
  if (b < NB) {
    int i = b * 256 + t;
    if (i < N) cnt[i] = 0;
    return;
  }
  if (b == NB) {
    __shared__ unsigned sh[256];
    unsigned acc = 0;
    for (int i = 1 + 2 * t; i < 8192; i += 512) acc |= raw[i];
    sh[t] = acc;
    __syncthreads();
    for (int s = 128; s > 0; s >>= 1) {
      if (t < s) sh[t] |= sh[t + s];
      __syncthreads();
    }
    if (t == 0) *flag = (sh[0] == 0u) ? 1u : 0u;  // 1 => int64
    return;
  }
  int idx = (b - NB - 1) * 256 + t;
  const int S1 = C_IN * C_HID;
  if (idx >= S1 + C_HID * C_OUT) return;
  const float* W; ushort_t *hi, *lo; int K, Nn, li;
  if (idx < S1) { W = W1; hi = h1; lo = l1; K = C_IN; Nn = C_HID; li = idx; }
  else { W = W2; hi = h2; lo = l2; K = C_HID; Nn = C_OUT; li = idx - S1; }
  int k = li / Nn, n = li - k * Nn;
  float v = W[li];
  ushort_t h = f2bf(v);
  hi[(size_t)n * K + k] = h;
  lo[(size_t)n * K + k] = f2bf(v - bf2f(h));
}

// dst-degree histogram straight from raw edges (cnt pre-zeroed)
__global__ __launch_bounds__(256) void k_hist(const void* __restrict__ raw,
                                              const unsigned* __restrict__ flag,
                                              int* __restrict__ cnt, int E) {
  int e = blockIdx.x * 256 + threadIdx.x;
  if (e >= E) return;
  int d;
  if (*flag) d = (int)((const long long*)raw)[E + e];
  else       d = ((const int*)raw)[E + e];
  atomicAdd(&cnt[d], 1);
}

// ---------------- single-block scan: 16 waves, shfl-based, 10 chunks --------
__global__ __launch_bounds__(1024) void k_scan(const int* __restrict__ cnt,
                                               int* __restrict__ roff,
                                               int* __restrict__ cursor,
                                               float* __restrict__ dinv,
                                               int n, int E) {
  __shared__ int wsum[16];
  __shared__ int sbase;
  int t = threadIdx.x;
  int lane = t & 63, w = t >> 6;
  if (t == 0) sbase = 0;
  __syncthreads();
  for (int c0 = 0; c0 < n; c0 += 1024) {
    int i = c0 + t;
    int v = (i < n) ? cnt[i] : 0;
    int sc = v;                                   // inclusive wave scan
#pragma unroll
    for (int d = 1; d < 64; d <<= 1) {
      int u = __shfl_up(sc, d);
      if (lane >= d) sc += u;
    }
    if (lane == 63) wsum[w] = sc;
    __syncthreads();
    int wpre = 0;
#pragma unroll
    for (int k = 0; k < 16; ++k) wpre += (k < w) ? wsum[k] : 0;
    int base = sbase;
    if (i < n) {
      int excl = base + wpre + sc - v;
      roff[i] = excl;
      cursor[i] = excl;
      dinv[i] = rsqrtf((float)(v + 1));           // +1 self-loop
    }
    __syncthreads();
    if (t == 1023) sbase = base + wpre + sc;
    __syncthreads();
  }
  if (t == 0) roff[n] = E;
}

__global__ __launch_bounds__(256) void k_scatter(const void* __restrict__ raw,
                                                 const unsigned* __restrict__ flag,
                                                 int* __restrict__ cursor,
                                                 int* __restrict__ csr, int E) {
  int e = blockIdx.x * 256 + threadIdx.x;
  if (e >= E) return;
  int s, d;
  if (*flag) {
    s = (int)((const long long*)raw)[e];
    d = (int)((const long long*)raw)[E + e];
  } else {
    s = ((const int*)raw)[e];
    d = ((const int*)raw)[E + e];
  }
  int slot = atomicAdd(&cursor[d], 1);
  csr[slot] = s;
}

// ---------------- gather: 4 nodes/block, csr-prefetch dbuf, unroll-8 --------
template <int EPI, int PRE>
__global__ __launch_bounds__(256) void k_gather4(const int* __restrict__ roff,
                                                 const int* __restrict__ csr,
                                                 const float* __restrict__ dinv,
                                                 const float* __restrict__ x,
                                                 const float* __restrict__ bias,
                                                 void* __restrict__ o1,
                                                 void* __restrict__ o2,
                                                 unsigned dk0, unsigned dk1) {
  int g = threadIdx.x >> 6;
  int tg = threadIdx.x & 63;
  int node = blockIdx.x * 4 + g;
  float dd = dinv[node];
  const float4* xr = (const float4*)x;
  float4 v = xr[(size_t)node * 64 + tg];
  float4 acc;
  if (PRE) acc = v;
  else acc = make_float4(dd * v.x, dd * v.y, dd * v.z, dd * v.w);
  int p = roff[node], end = roff[node + 1];
  int s[8];
  bool have = (p + 8 <= end);
  if (have) {
#pragma unroll
    for (int q = 0; q < 8; ++q) s[q] = csr[p + q];
  }
  while (have) {
    int sn[8];
    bool haven = (p + 16 <= end);
    if (haven) {
#pragma unroll
      for (int q = 0; q < 8; ++q) sn[q] = csr[p + 8 + q];
    }
    float4 r[8];
#pragma unroll
    for (int q = 0; q < 8; ++q) r[q] = xr[(size_t)s[q] * 64 + tg];
    if (PRE) {
#pragma unroll
      for (int q = 0; q < 8; ++q) {
        acc.x += r[q].x; acc.y += r[q].y; acc.z += r[q].z; acc.w += r[q].w;
      }
    } else {
      float w[8];
#pragma unroll
      for (int q = 0; q < 8; ++q) w[q] = dinv[s[q]];
#pragma unroll
      for (int q = 0; q < 8; ++q) {
        acc.x += w[q] * r[q].x; acc.y += w[q] * r[q].y;
        acc.z += w[q] * r[q].z; acc.w += w[q] * r[q].w;
      }
    }
    p += 8;
#pragma unroll
    for (int q = 0; q < 8; ++q) s[q] = sn[q];
    have = haven;
  }
  for (; p + 4 <= end; p += 4) {
    int s0 = csr[p], s1 = csr[p + 1], s2 = csr[p + 2], s3 = csr[p + 3];
    float4 a = xr[(size_t)s0 * 64 + tg];
    float4 b = xr[(size_t)s1 * 64 + tg];
    float4 c = xr[(size_t)s2 * 64 + tg];
    float4 d = xr[(size_t)s3 * 64 + tg];
    if (PRE) {
      acc.x += a.x + b.x + c.x + d.x;
      acc.y += a.y + b.y + c.y + d.y;
      acc.z += a.z + b.z + c.z + d.z;
      acc.w += a.w + b.w + c.w + d.w;
    } else {
      float w0 = dinv[s0], w1 = dinv[s1], w2 = dinv[s2], w3 = dinv[s3];
      acc.x += w0 * a.x + w1 * b.x + w2 * c.x + w3 * d.x;
      acc.y += w0 * a.y + w1 * b.y + w2 * c.y + w3 * d.y;
      acc.z += w0 * a.z + w1 * b.z + w2 * c.z + w3 * d.z;
      acc.w += w0 * a.w + w1 * b.w + w2 * c.w + w3 * d.w;
    }
  }
  for (; p < end; ++p) {
    int s0 = csr[p];
    float4 a = xr[(size_t)s0 * 64 + tg];
    if (PRE) {
      acc.x += a.x; acc.y += a.y; acc.z += a.z; acc.w += a.w;
    } else {
      float w0 = dinv[s0];
      acc.x += w0 * a.x; acc.y += w0 * a.y; acc.z += w0 * a.z; acc.w += w0 * a.w;
    }
  }
  acc.x *= dd; acc.y *= dd; acc.z *= dd; acc.w *= dd;
  if (EPI) {
    float4 bb = ((const float4*)bias)[tg];
    acc.x = fmaxf(acc.x + bb.x, 0.0f);
    acc.y = fmaxf(acc.y + bb.y, 0.0f);
    acc.z = fmaxf(acc.z + bb.z, 0.0f);
    acc.w = fmaxf(acc.w + bb.w, 0.0f);
    unsigned jb = (unsigned)node * 256u + (unsigned)tg * 4u;
    acc.x *= drop_scale(jb + 0u, dk0, dk1);
    acc.y *= drop_scale(jb + 1u, dk0, dk1);
    acc.z *= drop_scale(jb + 2u, dk0, dk1);
    acc.w *= drop_scale(jb + 3u, dk0, dk1);
    ((float4*)o1)[(size_t)node * 64 + tg] = acc;
  } else {
    ushort_t h0 = f2bf(acc.x), h1 = f2bf(acc.y), h2 = f2bf(acc.z), h3 = f2bf(acc.w);
    ushort4 hv = make_ushort4(h0, h1, h2, h3);
    ushort4 lv = make_ushort4(f2bf(acc.x - bf2f(h0)), f2bf(acc.y - bf2f(h1)),
                              f2bf(acc.z - bf2f(h2)), f2bf(acc.w - bf2f(h3)));
    ((ushort4*)o1)[(size_t)node * 64 + tg] = hv;
    ((ushort4*)o2)[(size_t)node * 64 + tg] = lv;
  }
}

// ---------------- bf16x3 MFMA GEMM: 64x128 tile, dbuf gll16 + counted vmcnt -
template <int EPI>
__global__ __launch_bounds__(256) void k_gemm3(
    const ushort_t* __restrict__ Ahi, const ushort_t* __restrict__ Alo,
    const ushort_t* __restrict__ Bhi, const ushort_t* __restrict__ Blo,
    const float* __restrict__ bias, const float* __restrict__ dscale,
    ushort_t* __restrict__ Chi, ushort_t* __restrict__ Clo,
    float* __restrict__ Cf,
    int M, int N, int K, unsigned dk0, unsigned dk1) {
  __shared__ ushort_t sAh[2][64 * 32], sAl[2][64 * 32];
  __shared__ ushort_t sBh[2][128 * 32], sBl[2][128 * 32];
  const int t = threadIdx.x;
  const int lane = t & 63, wave = t >> 6;
  const int wm = wave & 1, wn = wave >> 1;
  const int quad = lane >> 4, l16 = lane & 15;
  const int row0 = blockIdx.y * 64, col0 = blockIdx.x * 128;
  const int srow = t >> 2;
  const int skc = (((t & 3) ^ ((t >> 3) & 3)) * 8);   // swizzled source chunk
  const int qx8 = (quad ^ ((l16 >> 1) & 3)) * 8;      // swizzled read chunk

  floatx4 acc[2][4] = {};

  const int ra  = min(row0 + srow, M - 1);
  const int rb0 = col0 + srow;
  const int rb1 = col0 + 64 + srow;

  const ushort_t* gAh = Ahi + (size_t)ra * K + skc;
  const ushort_t* gAl = Alo + (size_t)ra * K + skc;
  const ushort_t* gB0h = Bhi + (size_t)rb0 * K + skc;
  const ushort_t* gB1h = Bhi + (size_t)rb1 * K + skc;
  const ushort_t* gB0l = Blo + (size_t)rb0 * K + skc;
  const ushort_t* gB1l = Blo + (size_t)rb1 * K + skc;

#define STAGE(c, kt) {                                  \
    gll16(gAh + (kt), &sAh[c][wave * 512]);             \
    gll16(gAl + (kt), &sAl[c][wave * 512]);             \
    gll16(gB0h + (kt), &sBh[c][wave * 512]);            \
    gll16(gB1h + (kt), &sBh[c][2048 + wave * 512]);     \
    gll16(gB0l + (kt), &sBl[c][wave * 512]);            \
    gll16(gB1l + (kt), &sBl[c][2048 + wave * 512]); }

  const int nk = K >> 5;
  STAGE(0, 0)
  for (int it = 0; it < nk; ++it) {
    const int c = it & 1;
    if (it + 1 < nk) {
      STAGE(c ^ 1, (it + 1) * 32)
      asm volatile("s_waitcnt vmcnt(6)\n\ts_barrier" ::: "memory");
    } else {
      asm volatile("s_waitcnt vmcnt(0)\n\ts_barrier" ::: "memory");
    }

    bf16x8 ah[2], al[2], bh[4], bl[4];
#pragma unroll
    for (int i = 0; i < 2; ++i) {
      int off = (wm * 32 + i * 16 + l16) * 32 + qx8;
      ah[i] = *(const bf16x8*)&sAh[c][off];
      al[i] = *(const bf16x8*)&sAl[c][off];
    }
#pragma unroll
    for (int j = 0; j < 4; ++j) {
      int off = (wn * 64 + j * 16 + l16) * 32 + qx8;
      bh[j] = *(const bf16x8*)&sBh[c][off];
      bl[j] = *(const bf16x8*)&sBl[c][off];
    }
#pragma unroll
    for (int i = 0; i < 2; ++i)
#pragma unroll
      for (int j = 0; j < 4; ++j) {
        acc[i][j] = __builtin_amdgcn_mfma_f32_16x16x32_bf16(ah[i], bh[j], acc[i][j], 0, 0, 0);
        acc[i][j] = __builtin_amdgcn_mfma_f32_16x16x32_bf16(ah[i], bl[j], acc[i][j], 0, 0, 0);
        acc[i][j] = __builtin_amdgcn_mfma_f32_16x16x32_bf16(al[i], bh[j], acc[i][j], 0, 0, 0);
      }
    asm volatile("s_barrier" ::: "memory");
  }
#undef STAGE

#pragma unroll
  for (int i = 0; i < 2; ++i) {
#pragma unroll
    for (int j = 0; j < 4; ++j) {
      int gc = col0 + wn * 64 + j * 16 + l16;
#pragma unroll
      for (int reg = 0; reg < 4; ++reg) {
        int gr = row0 + wm * 32 + i * 16 + quad * 4 + reg;
        if (gr >= M) continue;
        float v = acc[i][j][reg];
        size_t o = (size_t)gr * N + gc;
        if (EPI) {
          v += bias[gc];
          v = fmaxf(v, 0.0f);
          v *= drop_scale((unsigned)gr * (unsigned)N + (unsigned)gc, dk0, dk1);
          ushort_t h = f2bf(v);
          Chi[o] = h;
          Clo[o] = f2bf(v - bf2f(h));
        } else {
          Cf[o] = v * dscale[gr];
        }
      }
    }
  }
}

extern "C" void kernel_launch(void* const* d_in, const int* in_sizes, int n_in,
                              void* d_out, int out_size, void* d_ws, size_t ws_size,
                              hipStream_t stream) {
  const float* x  = (const float*)d_in[0];
  const void*  ei = d_in[1];
  const float* W1 = (const float*)d_in[2];
  const float* b1 = (const float*)d_in[3];
  const float* W2 = (const float*)d_in[4];
  const float* b2 = (const float*)d_in[5];
  float* out = (float*)d_out;

  const int N = in_sizes[0] / C_IN;   // 10000
  const int E = in_sizes[1] / 2;      // 160000
  const int NB = (N + 255) / 256;     // 40

  unsigned a0 = 0u, a1 = 0u, b0 = 0u, b1k = 1u;
  tf_rounds(a0, a1, 0u, 42u);   // dk1
  tf_rounds(b0, b1k, 0u, 42u);  // dk2

  uintptr_t base = (uintptr_t)d_ws;
  unsigned*  flag   = (unsigned*)base;
  int*       cnt    = (int*)(base + 16 * 1024);
  int*       roff   = (int*)(base + 64 * 1024);
  int*       cursor = (int*)(base + 128 * 1024);
  float*     dinv   = (float*)(base + 192 * 1024);
  int*       csr    = (int*)(base + 2u * 1024 * 1024);
  ushort_t*  Ahi    = (ushort_t*)(base + 4u  * 1024 * 1024);
  ushort_t*  Alo    = (ushort_t*)(base + 10u * 1024 * 1024);
  ushort_t*  H1hi   = (ushort_t*)(base + 16u * 1024 * 1024);
  ushort_t*  H1lo   = (ushort_t*)(base + 27u * 1024 * 1024);
  float*     hw2    = (float*)(base + 38u * 1024 * 1024);
  ushort_t*  W1thi  = (ushort_t*)(base + 49u * 1024 * 1024);
  ushort_t*  W1tlo  = (ushort_t*)(base + 49u * 1024 * 1024 + 512 * 1024);
  ushort_t*  W2thi  = (ushort_t*)(base + 50u * 1024 * 1024);
  ushort_t*  W2tlo  = (ushort_t*)(base + 50u * 1024 * 1024 + 512 * 1024);

  dim3 b256(256);
  const int WCB = (C_IN * C_HID + C_HID * C_OUT + 255) / 256;

  // 1. fused setup: zero cnt | detect | weight convert
  k_setup<<<dim3(NB + 1 + WCB), b256, 0, stream>>>((const unsigned*)ei, flag, cnt,
                                                   N, NB, W1, W2,
                                                   W1thi, W1tlo, W2thi, W2tlo);
  // 2. degree histogram (reads raw dst half)
  k_hist<<<dim3((E + 255) / 256), b256, 0, stream>>>(ei, flag, cnt, E);
  // 3. single-block scan -> roff/cursor/dinv
  k_scan<<<dim3(1), dim3(1024), 0, stream>>>(cnt, roff, cursor, dinv, N, E);
  // 4. CSR scatter (reads raw directly)
  k_scatter<<<dim3((E + 255) / 256), b256, 0, stream>>>(ei, flag, cursor, csr, E);
  // 5. layer 1 aggregate -> bf16 split A   [x2: duplicated for cost measurement]
  k_gather4<0, 0><<<dim3(N / 4), b256, 0, stream>>>(roff, csr, dinv, x, nullptr,
                                                    Ahi, Alo, 0u, 0u);
  k_gather4<0, 0><<<dim3(N / 4), b256, 0, stream>>>(roff, csr, dinv, x, nullptr,
                                                    Ahi, Alo, 0u, 0u);
  // 6. h1 = drop(relu(agg @ W1 + b1))
  k_gemm3<1><<<dim3(C_HID / 128, (N + 63) / 64), b256, 0, stream>>>(
      Ahi, Alo, W1thi, W1tlo, b1, nullptr, H1hi, H1lo, nullptr,
      N, C_HID, C_IN, a0, a1);
  // 7. hw2' = dinv * (h1 @ W2)
  k_gemm3<0><<<dim3(C_OUT / 128, (N + 63) / 64), b256, 0, stream>>>(
      H1hi, H1lo, W2thi, W2tlo, nullptr, dinv, nullptr, nullptr, hw2,
      N, C_OUT, C_HID, 0u, 0u);
  // 8. out = drop(relu(...))   [x2: duplicated for cost measurement]
  k_gather4<1, 1><<<dim3(N / 4), b256, 0, stream>>>(roff, csr, dinv, hw2, b2,
                                                    out, nullptr, b0, b1k);
  k_gather4<1, 1><<<dim3(N / 4), b256, 0, stream>>>(roff, csr, dinv, hw2, b2,
                                                    out, nullptr, b0, b1k);
}

// Round 5
// 236.612 us; speedup vs baseline: 1.0394x; 1.0394x over previous
//
#include <hip/hip_runtime.h>
#include <stdint.h>

// GCN 2-layer: out = drop(relu(A_hat * (drop(relu((A_hat*X)*W1+b1)) * W2) + b2))
// v6: fused gather1+gemm1 (A resident in LDS, B-only dbuf staging, 512thr/32 nodes),
//     gemm2 duplicated (idempotent) to decode GEMM-vs-bubble cost next round.

#define C_IN 256
#define C_HID 512
#define C_OUT 256

typedef unsigned short ushort_t;
typedef __bf16 bf16x8 __attribute__((ext_vector_type(8)));
typedef float floatx4 __attribute__((ext_vector_type(4)));

typedef __attribute__((address_space(1))) const void g1_void;
typedef __attribute__((address_space(3))) void l3_void;

__device__ __forceinline__ void gll16(const ushort_t* g, ushort_t* l) {
  __builtin_amdgcn_global_load_lds((g1_void*)g, (l3_void*)l, 16, 0, 0);
}

// ---------------- Threefry-2x32 (matches JAX) ----------------
__host__ __device__ __forceinline__ void tf_rounds(unsigned& x0, unsigned& x1,
                                                   unsigned k0, unsigned k1) {
  unsigned k2 = k0 ^ k1 ^ 0x1BD11BDAu;
#define ROT(r) { x0 += x1; x1 = (x1 << r) | (x1 >> (32 - r)); x1 ^= x0; }
  x0 += k0; x1 += k1;
  ROT(13) ROT(15) ROT(26) ROT(6)
  x0 += k1; x1 += k2 + 1u;
  ROT(17) ROT(29) ROT(16) ROT(24)
  x0 += k2; x1 += k0 + 2u;
  ROT(13) ROT(15) ROT(26) ROT(6)
  x0 += k0; x1 += k1 + 3u;
  ROT(17) ROT(29) ROT(16) ROT(24)
  x0 += k1; x1 += k2 + 4u;
  ROT(13) ROT(15) ROT(26) ROT(6)
  x0 += k2; x1 += k0 + 5u;
#undef ROT
}

__device__ __forceinline__ float drop_scale(unsigned j, unsigned k0, unsigned k1) {
  unsigned x0 = 0u, x1 = j;
  tf_rounds(x0, x1, k0, k1);
  unsigned bits = x0 ^ x1;
  float u = __uint_as_float((bits >> 9) | 0x3f800000u) - 1.0f;
  return (u < 0.5f) ? 2.0f : 0.0f;
}

// bf16 helpers (RNE)
__device__ __forceinline__ ushort_t f2bf(float f) {
  unsigned u = __float_as_uint(f);
  unsigned r = (u + 0x7fffu + ((u >> 16) & 1u)) >> 16;
  return (ushort_t)r;
}
__device__ __forceinline__ float bf2f(ushort_t h) {
  return __uint_as_float(((unsigned)h) << 16);
}

// ---------------- fused setup: zero cnt | detect dtype | weight convert ----
__global__ __launch_bounds__(256) void k_setup(const unsigned* __restrict__ raw,
                                               unsigned* __restrict__ flag,
                                               int* __restrict__ cnt, int N, int NB,
                                               const float* __restrict__ W1,
                                               const float* __restrict__ W2,
                                               ushort_t* __restrict__ h1,
                                               ushort_t* __restrict__ l1,
                                               ushort_t* __restrict__ h2,
                                               ushort_t* __restrict__ l2) {
  int b = blockIdx.x, t = threadIdx.x;
  if (b < NB) {
    int i = b * 256 + t;
    if (i < N) cnt[i] = 0;
    return;
  }
  if (b == NB) {
    __shared__ unsigned sh[256];
    unsigned acc = 0;
    for (int i = 1 + 2 * t; i < 8192; i += 512) acc |= raw[i];
    sh[t] = acc;
    __syncthreads();
    for (int s = 128; s > 0; s >>= 1) {
      if (t < s) sh[t] |= sh[t + s];
      __syncthreads();
    }
    if (t == 0) *flag = (sh[0] == 0u) ? 1u : 0u;  // 1 => int64
    return;
  }
  int idx = (b - NB - 1) * 256 + t;
  const int S1 = C_IN * C_HID;
  if (idx >= S1 + C_HID * C_OUT) return;
  const float* W; ushort_t *hi, *lo; int K, Nn, li;
  if (idx < S1) { W = W1; hi = h1; lo = l1; K = C_IN; Nn = C_HID; li = idx; }
  else { W = W2; hi = h2; lo = l2; K = C_HID; Nn = C_OUT; li = idx - S1; }
  int k = li / Nn, n = li - k * Nn;
  float v = W[li];
  ushort_t h = f2bf(v);
  hi[(size_t)n * K + k] = h;
  lo[(size_t)n * K + k] = f2bf(v - bf2f(h));
}

// dst-degree histogram straight from raw edges (cnt pre-zeroed)
__global__ __launch_bounds__(256) void k_hist(const void* __restrict__ raw,
                                              const unsigned* __restrict__ flag,
                                              int* __restrict__ cnt, int E) {
  int e = blockIdx.x * 256 + threadIdx.x;
  if (e >= E) return;
  int d;
  if (*flag) d = (int)((const long long*)raw)[E + e];
  else       d = ((const int*)raw)[E + e];
  atomicAdd(&cnt[d], 1);
}

// ---------------- single-block scan: 16 waves, shfl-based ----------------
__global__ __launch_bounds__(1024) void k_scan(const int* __restrict__ cnt,
                                               int* __restrict__ roff,
                                               int* __restrict__ cursor,
                                               float* __restrict__ dinv,
                                               int n, int E) {
  __shared__ int wsum[16];
  __shared__ int sbase;
  int t = threadIdx.x;
  int lane = t & 63, w = t >> 6;
  if (t == 0) sbase = 0;
  __syncthreads();
  for (int c0 = 0; c0 < n; c0 += 1024) {
    int i = c0 + t;
    int v = (i < n) ? cnt[i] : 0;
    int sc = v;
#pragma unroll
    for (int d = 1; d < 64; d <<= 1) {
      int u = __shfl_up(sc, d);
      if (lane >= d) sc += u;
    }
    if (lane == 63) wsum[w] = sc;
    __syncthreads();
    int wpre = 0;
#pragma unroll
    for (int k = 0; k < 16; ++k) wpre += (k < w) ? wsum[k] : 0;
    int base = sbase;
    if (i < n) {
      int excl = base + wpre + sc - v;
      roff[i] = excl;
      cursor[i] = excl;
      dinv[i] = rsqrtf((float)(v + 1));
    }
    __syncthreads();
    if (t == 1023) sbase = base + wpre + sc;
    __syncthreads();
  }
  if (t == 0) roff[n] = E;
}

__global__ __launch_bounds__(256) void k_scatter(const void* __restrict__ raw,
                                                 const unsigned* __restrict__ flag,
                                                 int* __restrict__ cursor,
                                                 int* __restrict__ csr, int E) {
  int e = blockIdx.x * 256 + threadIdx.x;
  if (e >= E) return;
  int s, d;
  if (*flag) {
    s = (int)((const long long*)raw)[e];
    d = (int)((const long long*)raw)[E + e];
  } else {
    s = ((const int*)raw)[e];
    d = ((const int*)raw)[E + e];
  }
  int slot = atomicAdd(&cursor[d], 1);
  csr[slot] = s;
}

// ---------------- fused gather1 + gemm1 ----------------
// 512 threads, 32 nodes/block (grid 313). Phase A: gather 32 rows into LDS as
// bf16 hi/lo (8-way chunk-XOR swizzle). Phase B: 4 col-blocks x 8 K-steps,
// B-only dbuf staging (gll16, vmcnt(2)), A read from resident LDS.
__global__ __launch_bounds__(512) void k_fused1(
    const int* __restrict__ roff, const int* __restrict__ csr,
    const float* __restrict__ dinv, const float* __restrict__ x,
    const ushort_t* __restrict__ Bh, const ushort_t* __restrict__ Bl,
    const float* __restrict__ bias,
    ushort_t* __restrict__ Chi, ushort_t* __restrict__ Clo,
    int N, unsigned dk0, unsigned dk1) {
  __shared__ ushort_t sA[2 * 32 * 256];          // hi [0,8192), lo [8192,16384)
  __shared__ ushort_t sBh[2][128 * 32], sBl[2][128 * 32];
  const int t = threadIdx.x;
  const int lane = t & 63, wave = t >> 6;
  const int g = wave;                             // 0..7 (gather node group)
  const int tg = lane;

  // ---- Phase A: gather 32 nodes (4 rounds x 8 waves) ----
  const float4* xr = (const float4*)x;
#pragma unroll 1
  for (int rnd = 0; rnd < 4; ++rnd) {
    int lr = rnd * 8 + g;
    int node = blockIdx.x * 32 + lr;
    float4 acc = make_float4(0.f, 0.f, 0.f, 0.f);
    if (node < N) {
      float dd = dinv[node];
      float4 v = xr[(size_t)node * 64 + tg];
      acc = make_float4(dd * v.x, dd * v.y, dd * v.z, dd * v.w);
      int p = roff[node], end = roff[node + 1];
      int s[8];
      bool have = (p + 8 <= end);
      if (have) {
#pragma unroll
        for (int q = 0; q < 8; ++q) s[q] = csr[p + q];
      }
      while (have) {
        int sn[8];
        bool haven = (p + 16 <= end);
        if (haven) {
#pragma unroll
          for (int q = 0; q < 8; ++q) sn[q] = csr[p + 8 + q];
        }
        float w[8];
        float4 r[8];
#pragma unroll
        for (int q = 0; q < 8; ++q) r[q] = xr[(size_t)s[q] * 64 + tg];
#pragma unroll
        for (int q = 0; q < 8; ++q) w[q] = dinv[s[q]];
#pragma unroll
        for (int q = 0; q < 8; ++q) {
          acc.x += w[q] * r[q].x; acc.y += w[q] * r[q].y;
          acc.z += w[q] * r[q].z; acc.w += w[q] * r[q].w;
        }
        p += 8;
#pragma unroll
        for (int q = 0; q < 8; ++q) s[q] = sn[q];
        have = haven;
      }
      for (; p < end; ++p) {
        int s0 = csr[p];
        float w0 = dinv[s0];
        float4 a = xr[(size_t)s0 * 64 + tg];
        acc.x += w0 * a.x; acc.y += w0 * a.y; acc.z += w0 * a.z; acc.w += w0 * a.w;
      }
      acc.x *= dd; acc.y *= dd; acc.z *= dd; acc.w *= dd;
    }
    // bf16 split + swizzled LDS write: col c=4tg, chunk ch=tg>>1, pos ch^(lr&7)
    ushort_t h0 = f2bf(acc.x), h1 = f2bf(acc.y), h2 = f2bf(acc.z), h3 = f2bf(acc.w);
    ushort4 hv = make_ushort4(h0, h1, h2, h3);
    ushort4 lv = make_ushort4(f2bf(acc.x - bf2f(h0)), f2bf(acc.y - bf2f(h1)),
                              f2bf(acc.z - bf2f(h2)), f2bf(acc.w - bf2f(h3)));
    int chs = (tg >> 1) ^ (lr & 7);
    int off = lr * 256 + chs * 8 + 4 * (tg & 1);
    *(ushort4*)&sA[off] = hv;
    *(ushort4*)&sA[8192 + off] = lv;
  }
  __syncthreads();

  // ---- Phase B: gemm1 (32 x 512, K=256), B-only staging ----
  const int wm = wave & 1, wn = wave >> 1;        // wm:rows(2x16), wn:cols(4x32)
  const int quad = lane >> 4, l16 = lane & 15;
  const int srow = t >> 2;                        // 0..127 (B stage row)
  const int skc = (((t & 3) ^ ((t >> 3) & 3)) * 8);
  const int qx8 = (quad ^ ((l16 >> 1) & 3)) * 8;
  const ushort_t* gBh = Bh + (size_t)srow * 256 + skc;
  const ushort_t* gBl = Bl + (size_t)srow * 256 + skc;

  floatx4 acc[2] = {};

#define STAGE1(c, scb, sk) {                               \
    gll16(gBh + (((scb) << 15) + (sk)), &sBh[c][t * 8]);   \
    gll16(gBl + (((scb) << 15) + (sk)), &sBl[c][t * 8]); }

  STAGE1(0, 0, 0)
#pragma unroll 2
  for (int s = 0; s < 32; ++s) {
    const int c = s & 1;
    if (s + 1 < 32) {
      const int sn1 = s + 1;
      STAGE1(c ^ 1, sn1 >> 3, (sn1 & 7) * 32)
      asm volatile("s_waitcnt vmcnt(2)\n\ts_barrier" ::: "memory");
    } else {
      asm volatile("s_waitcnt vmcnt(0)\n\ts_barrier" ::: "memory");
    }
    const int cb = s >> 3, kk = (s & 7) * 32;
    // A frags from resident LDS (swizzled)
    const int lrA = wm * 16 + l16;
    const int offA = lrA * 256 + (((kk >> 3) + quad) ^ (l16 & 7)) * 8;
    bf16x8 ah = *(const bf16x8*)&sA[offA];
    bf16x8 al = *(const bf16x8*)&sA[8192 + offA];
#pragma unroll
    for (int j = 0; j < 2; ++j) {
      const int offB = (wn * 32 + j * 16 + l16) * 32 + qx8;
      bf16x8 bh = *(const bf16x8*)&sBh[c][offB];
      bf16x8 bl = *(const bf16x8*)&sBl[c][offB];
      acc[j] = __builtin_amdgcn_mfma_f32_16x16x32_bf16(ah, bh, acc[j], 0, 0, 0);
      acc[j] = __builtin_amdgcn_mfma_f32_16x16x32_bf16(ah, bl, acc[j], 0, 0, 0);
      acc[j] = __builtin_amdgcn_mfma_f32_16x16x32_bf16(al, bh, acc[j], 0, 0, 0);
    }
    if ((s & 7) == 7) {  // col-block cb complete -> epilogue + reset
#pragma unroll
      for (int j = 0; j < 2; ++j) {
        int gc = cb * 128 + wn * 32 + j * 16 + l16;
#pragma unroll
        for (int reg = 0; reg < 4; ++reg) {
          int gr = blockIdx.x * 32 + wm * 16 + quad * 4 + reg;
          if (gr >= N) continue;
          float v = acc[j][reg];
          v += bias[gc];
          v = fmaxf(v, 0.0f);
          v *= drop_scale((unsigned)gr * (unsigned)C_HID + (unsigned)gc, dk0, dk1);
          size_t o = (size_t)gr * C_HID + gc;
          ushort_t h = f2bf(v);
          Chi[o] = h;
          Clo[o] = f2bf(v - bf2f(h));
        }
        acc[j] = (floatx4){0.f, 0.f, 0.f, 0.f};
      }
    }
    asm volatile("s_barrier" ::: "memory");
  }
#undef STAGE1
}

// ---------------- gather2: 4 nodes/block, csr-prefetch dbuf, unroll-8 -------
template <int EPI, int PRE>
__global__ __launch_bounds__(256) void k_gather4(const int* __restrict__ roff,
                                                 const int* __restrict__ csr,
                                                 const float* __restrict__ dinv,
                                                 const float* __restrict__ x,
                                                 const float* __restrict__ bias,
                                                 void* __restrict__ o1,
                                                 void* __restrict__ o2,
                                                 unsigned dk0, unsigned dk1) {
  int g = threadIdx.x >> 6;
  int tg = threadIdx.x & 63;
  int node = blockIdx.x * 4 + g;
  float dd = dinv[node];
  const float4* xr = (const float4*)x;
  float4 v = xr[(size_t)node * 64 + tg];
  float4 acc;
  if (PRE) acc = v;
  else acc = make_float4(dd * v.x, dd * v.y, dd * v.z, dd * v.w);
  int p = roff[node], end = roff[node + 1];
  int s[8];
  bool have = (p + 8 <= end);
  if (have) {
#pragma unroll
    for (int q = 0; q < 8; ++q) s[q] = csr[p + q];
  }
  while (have) {
    int sn[8];
    bool haven = (p + 16 <= end);
    if (haven) {
#pragma unroll
      for (int q = 0; q < 8; ++q) sn[q] = csr[p + 8 + q];
    }
    float4 r[8];
#pragma unroll
    for (int q = 0; q < 8; ++q) r[q] = xr[(size_t)s[q] * 64 + tg];
    if (PRE) {
#pragma unroll
      for (int q = 0; q < 8; ++q) {
        acc.x += r[q].x; acc.y += r[q].y; acc.z += r[q].z; acc.w += r[q].w;
      }
    } else {
      float w[8];
#pragma unroll
      for (int q = 0; q < 8; ++q) w[q] = dinv[s[q]];
#pragma unroll
      for (int q = 0; q < 8; ++q) {
        acc.x += w[q] * r[q].x; acc.y += w[q] * r[q].y;
        acc.z += w[q] * r[q].z; acc.w += w[q] * r[q].w;
      }
    }
    p += 8;
#pragma unroll
    for (int q = 0; q < 8; ++q) s[q] = sn[q];
    have = haven;
  }
  for (; p + 4 <= end; p += 4) {
    int s0 = csr[p], s1 = csr[p + 1], s2 = csr[p + 2], s3 = csr[p + 3];
    float4 a = xr[(size_t)s0 * 64 + tg];
    float4 b = xr[(size_t)s1 * 64 + tg];
    float4 c = xr[(size_t)s2 * 64 + tg];
    float4 d = xr[(size_t)s3 * 64 + tg];
    if (PRE) {
      acc.x += a.x + b.x + c.x + d.x;
      acc.y += a.y + b.y + c.y + d.y;
      acc.z += a.z + b.z + c.z + d.z;
      acc.w += a.w + b.w + c.w + d.w;
    } else {
      float w0 = dinv[s0], w1 = dinv[s1], w2 = dinv[s2], w3 = dinv[s3];
      acc.x += w0 * a.x + w1 * b.x + w2 * c.x + w3 * d.x;
      acc.y += w0 * a.y + w1 * b.y + w2 * c.y + w3 * d.y;
      acc.z += w0 * a.z + w1 * b.z + w2 * c.z + w3 * d.z;
      acc.w += w0 * a.w + w1 * b.w + w2 * c.w + w3 * d.w;
    }
  }
  for (; p < end; ++p) {
    int s0 = csr[p];
    float4 a = xr[(size_t)s0 * 64 + tg];
    if (PRE) {
      acc.x += a.x; acc.y += a.y; acc.z += a.z; acc.w += a.w;
    } else {
      float w0 = dinv[s0];
      acc.x += w0 * a.x; acc.y += w0 * a.y; acc.z += w0 * a.z; acc.w += w0 * a.w;
    }
  }
  acc.x *= dd; acc.y *= dd; acc.z *= dd; acc.w *= dd;
  if (EPI) {
    float4 bb = ((const float4*)bias)[tg];
    acc.x = fmaxf(acc.x + bb.x, 0.0f);
    acc.y = fmaxf(acc.y + bb.y, 0.0f);
    acc.z = fmaxf(acc.z + bb.z, 0.0f);
    acc.w = fmaxf(acc.w + bb.w, 0.0f);
    unsigned jb = (unsigned)node * 256u + (unsigned)tg * 4u;
    acc.x *= drop_scale(jb + 0u, dk0, dk1);
    acc.y *= drop_scale(jb + 1u, dk0, dk1);
    acc.z *= drop_scale(jb + 2u, dk0, dk1);
    acc.w *= drop_scale(jb + 3u, dk0, dk1);
    ((float4*)o1)[(size_t)node * 64 + tg] = acc;
  } else {
    ushort_t h0 = f2bf(acc.x), h1 = f2bf(acc.y), h2 = f2bf(acc.z), h3 = f2bf(acc.w);
    ushort4 hv = make_ushort4(h0, h1, h2, h3);
    ushort4 lv = make_ushort4(f2bf(acc.x - bf2f(h0)), f2bf(acc.y - bf2f(h1)),
                              f2bf(acc.z - bf2f(h2)), f2bf(acc.w - bf2f(h3)));
    ((ushort4*)o1)[(size_t)node * 64 + tg] = hv;
    ((ushort4*)o2)[(size_t)node * 64 + tg] = lv;
  }
}

// ---------------- bf16x3 MFMA GEMM (gemm2): 64x128 tile, dbuf gll16 ---------
template <int EPI>
__global__ __launch_bounds__(256) void k_gemm3(
    const ushort_t* __restrict__ Ahi, const ushort_t* __restrict__ Alo,
    const ushort_t* __restrict__ Bhi, const ushort_t* __restrict__ Blo,
    const float* __restrict__ bias, const float* __restrict__ dscale,
    ushort_t* __restrict__ Chi, ushort_t* __restrict__ Clo,
    float* __restrict__ Cf,
    int M, int N, int K, unsigned dk0, unsigned dk1) {
  __shared__ ushort_t sAh[2][64 * 32], sAl[2][64 * 32];
  __shared__ ushort_t sBh[2][128 * 32], sBl[2][128 * 32];
  const int t = threadIdx.x;
  const int lane = t & 63, wave = t >> 6;
  const int wm = wave & 1, wn = wave >> 1;
  const int quad = lane >> 4, l16 = lane & 15;
  const int row0 = blockIdx.y * 64, col0 = blockIdx.x * 128;
  const int srow = t >> 2;
  const int skc = (((t & 3) ^ ((t >> 3) & 3)) * 8);
  const int qx8 = (quad ^ ((l16 >> 1) & 3)) * 8;

  floatx4 acc[2][4] = {};

  const int ra  = min(row0 + srow, M - 1);
  const int rb0 = col0 + srow;
  const int rb1 = col0 + 64 + srow;

  const ushort_t* gAh = Ahi + (size_t)ra * K + skc;
  const ushort_t* gAl = Alo + (size_t)ra * K + skc;
  const ushort_t* gB0h = Bhi + (size_t)rb0 * K + skc;
  const ushort_t* gB1h = Bhi + (size_t)rb1 * K + skc;
  const ushort_t* gB0l = Blo + (size_t)rb0 * K + skc;
  const ushort_t* gB1l = Blo + (size_t)rb1 * K + skc;

#define STAGE(c, kt) {                                  \
    gll16(gAh + (kt), &sAh[c][wave * 512]);             \
    gll16(gAl + (kt), &sAl[c][wave * 512]);             \
    gll16(gB0h + (kt), &sBh[c][wave * 512]);            \
    gll16(gB1h + (kt), &sBh[c][2048 + wave * 512]);     \
    gll16(gB0l + (kt), &sBl[c][wave * 512]);            \
    gll16(gB1l + (kt), &sBl[c][2048 + wave * 512]); }

  const int nk = K >> 5;
  STAGE(0, 0)
  for (int it = 0; it < nk; ++it) {
    const int c = it & 1;
    if (it + 1 < nk) {
      STAGE(c ^ 1, (it + 1) * 32)
      asm volatile("s_waitcnt vmcnt(6)\n\ts_barrier" ::: "memory");
    } else {
      asm volatile("s_waitcnt vmcnt(0)\n\ts_barrier" ::: "memory");
    }

    bf16x8 ah[2], al[2], bh[4], bl[4];
#pragma unroll
    for (int i = 0; i < 2; ++i) {
      int off = (wm * 32 + i * 16 + l16) * 32 + qx8;
      ah[i] = *(const bf16x8*)&sAh[c][off];
      al[i] = *(const bf16x8*)&sAl[c][off];
    }
#pragma unroll
    for (int j = 0; j < 4; ++j) {
      int off = (wn * 64 + j * 16 + l16) * 32 + qx8;
      bh[j] = *(const bf16x8*)&sBh[c][off];
      bl[j] = *(const bf16x8*)&sBl[c][off];
    }
#pragma unroll
    for (int i = 0; i < 2; ++i)
#pragma unroll
      for (int j = 0; j < 4; ++j) {
        acc[i][j] = __builtin_amdgcn_mfma_f32_16x16x32_bf16(ah[i], bh[j], acc[i][j], 0, 0, 0);
        acc[i][j] = __builtin_amdgcn_mfma_f32_16x16x32_bf16(ah[i], bl[j], acc[i][j], 0, 0, 0);
        acc[i][j] = __builtin_amdgcn_mfma_f32_16x16x32_bf16(al[i], bh[j], acc[i][j], 0, 0, 0);
      }
    asm volatile("s_barrier" ::: "memory");
  }
#undef STAGE

#pragma unroll
  for (int i = 0; i < 2; ++i) {
#pragma unroll
    for (int j = 0; j < 4; ++j) {
      int gc = col0 + wn * 64 + j * 16 + l16;
#pragma unroll
      for (int reg = 0; reg < 4; ++reg) {
        int gr = row0 + wm * 32 + i * 16 + quad * 4 + reg;
        if (gr >= M) continue;
        float v = acc[i][j][reg];
        size_t o = (size_t)gr * N + gc;
        if (EPI) {
          v += bias[gc];
          v = fmaxf(v, 0.0f);
          v *= drop_scale((unsigned)gr * (unsigned)N + (unsigned)gc, dk0, dk1);
          ushort_t h = f2bf(v);
          Chi[o] = h;
          Clo[o] = f2bf(v - bf2f(h));
        } else {
          Cf[o] = v * dscale[gr];
        }
      }
    }
  }
}

extern "C" void kernel_launch(void* const* d_in, const int* in_sizes, int n_in,
                              void* d_out, int out_size, void* d_ws, size_t ws_size,
                              hipStream_t stream) {
  const float* x  = (const float*)d_in[0];
  const void*  ei = d_in[1];
  const float* W1 = (const float*)d_in[2];
  const float* b1 = (const float*)d_in[3];
  const float* W2 = (const float*)d_in[4];
  const float* b2 = (const float*)d_in[5];
  float* out = (float*)d_out;

  const int N = in_sizes[0] / C_IN;   // 10000
  const int E = in_sizes[1] / 2;      // 160000
  const int NB = (N + 255) / 256;     // 40

  unsigned a0 = 0u, a1 = 0u, b0 = 0u, b1k = 1u;
  tf_rounds(a0, a1, 0u, 42u);   // dk1
  tf_rounds(b0, b1k, 0u, 42u);  // dk2

  uintptr_t base = (uintptr_t)d_ws;
  unsigned*  flag   = (unsigned*)base;
  int*       cnt    = (int*)(base + 16 * 1024);
  int*       roff   = (int*)(base + 64 * 1024);
  int*       cursor = (int*)(base + 128 * 1024);
  float*     dinv   = (float*)(base + 192 * 1024);
  int*       csr    = (int*)(base + 2u * 1024 * 1024);
  ushort_t*  H1hi   = (ushort_t*)(base + 16u * 1024 * 1024);
  ushort_t*  H1lo   = (ushort_t*)(base + 27u * 1024 * 1024);
  float*     hw2    = (float*)(base + 38u * 1024 * 1024);
  ushort_t*  W1thi  = (ushort_t*)(base + 49u * 1024 * 1024);
  ushort_t*  W1tlo  = (ushort_t*)(base + 49u * 1024 * 1024 + 512 * 1024);
  ushort_t*  W2thi  = (ushort_t*)(base + 50u * 1024 * 1024);
  ushort_t*  W2tlo  = (ushort_t*)(base + 50u * 1024 * 1024 + 512 * 1024);

  dim3 b256(256);
  const int WCB = (C_IN * C_HID + C_HID * C_OUT + 255) / 256;

  // 1. fused setup: zero cnt | detect | weight convert
  k_setup<<<dim3(NB + 1 + WCB), b256, 0, stream>>>((const unsigned*)ei, flag, cnt,
                                                   N, NB, W1, W2,
                                                   W1thi, W1tlo, W2thi, W2tlo);
  // 2. degree histogram
  k_hist<<<dim3((E + 255) / 256), b256, 0, stream>>>(ei, flag, cnt, E);
  // 3. single-block scan
  k_scan<<<dim3(1), dim3(1024), 0, stream>>>(cnt, roff, cursor, dinv, N, E);
  // 4. CSR scatter
  k_scatter<<<dim3((E + 255) / 256), b256, 0, stream>>>(ei, flag, cursor, csr, E);
  // 5. fused gather1+gemm1 -> H1 (bf16 split)   [313 blocks x 512 thr]
  k_fused1<<<dim3((N + 31) / 32), dim3(512), 0, stream>>>(
      roff, csr, dinv, x, W1thi, W1tlo, b1, H1hi, H1lo, N, a0, a1);
  // 6-7. hw2' = dinv * (h1 @ W2)   [x2: duplicated for cost measurement]
  k_gemm3<0><<<dim3(C_OUT / 128, (N + 63) / 64), b256, 0, stream>>>(
      H1hi, H1lo, W2thi, W2tlo, nullptr, dinv, nullptr, nullptr, hw2,
      N, C_OUT, C_HID, 0u, 0u);
  k_gemm3<0><<<dim3(C_OUT / 128, (N + 63) / 64), b256, 0, stream>>>(
      H1hi, H1lo, W2thi, W2tlo, nullptr, dinv, nullptr, nullptr, hw2,
      N, C_OUT, C_HID, 0u, 0u);
  // 8. out = drop(relu(dd * (sum hw2'[nbrs] + hw2'[self]) + b2))
  k_gather4<1, 1><<<dim3(N / 4), b256, 0, stream>>>(roff, csr, dinv, hw2, b2,
                                                    out, nullptr, b0, b1k);
}

// Round 6
// 201.006 us; speedup vs baseline: 1.2236x; 1.1771x over previous
//
#include <hip/hip_runtime.h>
#include <stdint.h>

// GCN 2-layer: out = drop(relu(A_hat * (drop(relu((A_hat*X)*W1+b1)) * W2) + b2))
// v7: standalone high-TLP gathers (fused1 reverted: gather at 8 waves/CU lost 15us),
//     gemm1+gemm2 fused into k_gemm12 (row-local; H1 stays in LDS, never global),
//     dup gemm2 removed. 7 launches.

#define C_IN 256
#define C_HID 512
#define C_OUT 256

typedef unsigned short ushort_t;
typedef __bf16 bf16x8 __attribute__((ext_vector_type(8)));
typedef float floatx4 __attribute__((ext_vector_type(4)));

typedef __attribute__((address_space(1))) const void g1_void;
typedef __attribute__((address_space(3))) void l3_void;

__device__ __forceinline__ void gll16(const ushort_t* g, ushort_t* l) {
  __builtin_amdgcn_global_load_lds((g1_void*)g, (l3_void*)l, 16, 0, 0);
}

// ---------------- Threefry-2x32 (matches JAX) ----------------
__host__ __device__ __forceinline__ void tf_rounds(unsigned& x0, unsigned& x1,
                                                   unsigned k0, unsigned k1) {
  unsigned k2 = k0 ^ k1 ^ 0x1BD11BDAu;
#define ROT(r) { x0 += x1; x1 = (x1 << r) | (x1 >> (32 - r)); x1 ^= x0; }
  x0 += k0; x1 += k1;
  ROT(13) ROT(15) ROT(26) ROT(6)
  x0 += k1; x1 += k2 + 1u;
  ROT(17) ROT(29) ROT(16) ROT(24)
  x0 += k2; x1 += k0 + 2u;
  ROT(13) ROT(15) ROT(26) ROT(6)
  x0 += k0; x1 += k1 + 3u;
  ROT(17) ROT(29) ROT(16) ROT(24)
  x0 += k1; x1 += k2 + 4u;
  ROT(13) ROT(15) ROT(26) ROT(6)
  x0 += k2; x1 += k0 + 5u;
#undef ROT
}

__device__ __forceinline__ float drop_scale(unsigned j, unsigned k0, unsigned k1) {
  unsigned x0 = 0u, x1 = j;
  tf_rounds(x0, x1, k0, k1);
  unsigned bits = x0 ^ x1;
  float u = __uint_as_float((bits >> 9) | 0x3f800000u) - 1.0f;
  return (u < 0.5f) ? 2.0f : 0.0f;
}

// bf16 helpers (RNE)
__device__ __forceinline__ ushort_t f2bf(float f) {
  unsigned u = __float_as_uint(f);
  unsigned r = (u + 0x7fffu + ((u >> 16) & 1u)) >> 16;
  return (ushort_t)r;
}
__device__ __forceinline__ float bf2f(ushort_t h) {
  return __uint_as_float(((unsigned)h) << 16);
}

// ---------------- fused setup: zero cnt | detect dtype | weight convert ----
__global__ __launch_bounds__(256) void k_setup(const unsigned* __restrict__ raw,
                                               unsigned* __restrict__ flag,
                                               int* __restrict__ cnt, int N, int NB,
                                               const float* __restrict__ W1,
                                               const float* __restrict__ W2,
                                               ushort_t* __restrict__ h1,
                                               ushort_t* __restrict__ l1,
                                               ushort_t* __restrict__ h2,
                                               ushort_t* __restrict__ l2) {
  int b = blockIdx.x, t = threadIdx.x;
  if (b < NB) {
    int i = b * 256 + t;
    if (i < N) cnt[i] = 0;
    return;
  }
  if (b == NB) {
    __shared__ unsigned sh[256];
    unsigned acc = 0;
    for (int i = 1 + 2 * t; i < 8192; i += 512) acc |= raw[i];
    sh[t] = acc;
    __syncthreads();
    for (int s = 128; s > 0; s >>= 1) {
      if (t < s) sh[t] |= sh[t + s];
      __syncthreads();
    }
    if (t == 0) *flag = (sh[0] == 0u) ? 1u : 0u;  // 1 => int64
    return;
  }
  int idx = (b - NB - 1) * 256 + t;
  const int S1 = C_IN * C_HID;
  if (idx >= S1 + C_HID * C_OUT) return;
  const float* W; ushort_t *hi, *lo; int K, Nn, li;
  if (idx < S1) { W = W1; hi = h1; lo = l1; K = C_IN; Nn = C_HID; li = idx; }
  else { W = W2; hi = h2; lo = l2; K = C_HID; Nn = C_OUT; li = idx - S1; }
  int k = li / Nn, n = li - k * Nn;
  float v = W[li];
  ushort_t h = f2bf(v);
  hi[(size_t)n * K + k] = h;
  lo[(size_t)n * K + k] = f2bf(v - bf2f(h));
}

// dst-degree histogram straight from raw edges (cnt pre-zeroed)
__global__ __launch_bounds__(256) void k_hist(const void* __restrict__ raw,
                                              const unsigned* __restrict__ flag,
                                              int* __restrict__ cnt, int E) {
  int e = blockIdx.x * 256 + threadIdx.x;
  if (e >= E) return;
  int d;
  if (*flag) d = (int)((const long long*)raw)[E + e];
  else       d = ((const int*)raw)[E + e];
  atomicAdd(&cnt[d], 1);
}

// ---------------- single-block scan: 16 waves, shfl-based ----------------
__global__ __launch_bounds__(1024) void k_scan(const int* __restrict__ cnt,
                                               int* __restrict__ roff,
                                               int* __restrict__ cursor,
                                               float* __restrict__ dinv,
                                               int n, int E) {
  __shared__ int wsum[16];
  __shared__ int sbase;
  int t = threadIdx.x;
  int lane = t & 63, w = t >> 6;
  if (t == 0) sbase = 0;
  __syncthreads();
  for (int c0 = 0; c0 < n; c0 += 1024) {
    int i = c0 + t;
    int v = (i < n) ? cnt[i] : 0;
    int sc = v;
#pragma unroll
    for (int d = 1; d < 64; d <<= 1) {
      int u = __shfl_up(sc, d);
      if (lane >= d) sc += u;
    }
    if (lane == 63) wsum[w] = sc;
    __syncthreads();
    int wpre = 0;
#pragma unroll
    for (int k = 0; k < 16; ++k) wpre += (k < w) ? wsum[k] : 0;
    int base = sbase;
    if (i < n) {
      int excl = base + wpre + sc - v;
      roff[i] = excl;
      cursor[i] = excl;
      dinv[i] = rsqrtf((float)(v + 1));
    }
    __syncthreads();
    if (t == 1023) sbase = base + wpre + sc;
    __syncthreads();
  }
  if (t == 0) roff[n] = E;
}

__global__ __launch_bounds__(256) void k_scatter(const void* __restrict__ raw,
                                                 const unsigned* __restrict__ flag,
                                                 int* __restrict__ cursor,
                                                 int* __restrict__ csr, int E) {
  int e = blockIdx.x * 256 + threadIdx.x;
  if (e >= E) return;
  int s, d;
  if (*flag) {
    s = (int)((const long long*)raw)[e];
    d = (int)((const long long*)raw)[E + e];
  } else {
    s = ((const int*)raw)[e];
    d = ((const int*)raw)[E + e];
  }
  int slot = atomicAdd(&cursor[d], 1);
  csr[slot] = s;
}

// ---------------- gather: 4 nodes/block, csr-prefetch dbuf, unroll-8 --------
template <int EPI, int PRE>
__global__ __launch_bounds__(256) void k_gather4(const int* __restrict__ roff,
                                                 const int* __restrict__ csr,
                                                 const float* __restrict__ dinv,
                                                 const float* __restrict__ x,
                                                 const float* __restrict__ bias,
                                                 void* __restrict__ o1,
                                                 void* __restrict__ o2,
                                                 unsigned dk0, unsigned dk1) {
  int g = threadIdx.x >> 6;
  int tg = threadIdx.x & 63;
  int node = blockIdx.x * 4 + g;
  float dd = dinv[node];
  const float4* xr = (const float4*)x;
  float4 v = xr[(size_t)node * 64 + tg];
  float4 acc;
  if (PRE) acc = v;
  else acc = make_float4(dd * v.x, dd * v.y, dd * v.z, dd * v.w);
  int p = roff[node], end = roff[node + 1];
  int s[8];
  bool have = (p + 8 <= end);
  if (have) {
#pragma unroll
    for (int q = 0; q < 8; ++q) s[q] = csr[p + q];
  }
  while (have) {
    int sn[8];
    bool haven = (p + 16 <= end);
    if (haven) {
#pragma unroll
      for (int q = 0; q < 8; ++q) sn[q] = csr[p + 8 + q];
    }
    float4 r[8];
#pragma unroll
    for (int q = 0; q < 8; ++q) r[q] = xr[(size_t)s[q] * 64 + tg];
    if (PRE) {
#pragma unroll
      for (int q = 0; q < 8; ++q) {
        acc.x += r[q].x; acc.y += r[q].y; acc.z += r[q].z; acc.w += r[q].w;
      }
    } else {
      float w[8];
#pragma unroll
      for (int q = 0; q < 8; ++q) w[q] = dinv[s[q]];
#pragma unroll
      for (int q = 0; q < 8; ++q) {
        acc.x += w[q] * r[q].x; acc.y += w[q] * r[q].y;
        acc.z += w[q] * r[q].z; acc.w += w[q] * r[q].w;
      }
    }
    p += 8;
#pragma unroll
    for (int q = 0; q < 8; ++q) s[q] = sn[q];
    have = haven;
  }
  for (; p + 4 <= end; p += 4) {
    int s0 = csr[p], s1 = csr[p + 1], s2 = csr[p + 2], s3 = csr[p + 3];
    float4 a = xr[(size_t)s0 * 64 + tg];
    float4 b = xr[(size_t)s1 * 64 + tg];
    float4 c = xr[(size_t)s2 * 64 + tg];
    float4 d = xr[(size_t)s3 * 64 + tg];
    if (PRE) {
      acc.x += a.x + b.x + c.x + d.x;
      acc.y += a.y + b.y + c.y + d.y;
      acc.z += a.z + b.z + c.z + d.z;
      acc.w += a.w + b.w + c.w + d.w;
    } else {
      float w0 = dinv[s0], w1 = dinv[s1], w2 = dinv[s2], w3 = dinv[s3];
      acc.x += w0 * a.x + w1 * b.x + w2 * c.x + w3 * d.x;
      acc.y += w0 * a.y + w1 * b.y + w2 * c.y + w3 * d.y;
      acc.z += w0 * a.z + w1 * b.z + w2 * c.z + w3 * d.z;
      acc.w += w0 * a.w + w1 * b.w + w2 * c.w + w3 * d.w;
    }
  }
  for (; p < end; ++p) {
    int s0 = csr[p];
    float4 a = xr[(size_t)s0 * 64 + tg];
    if (PRE) {
      acc.x += a.x; acc.y += a.y; acc.z += a.z; acc.w += a.w;
    } else {
      float w0 = dinv[s0];
      acc.x += w0 * a.x; acc.y += w0 * a.y; acc.z += w0 * a.z; acc.w += w0 * a.w;
    }
  }
  acc.x *= dd; acc.y *= dd; acc.z *= dd; acc.w *= dd;
  if (EPI) {
    float4 bb = ((const float4*)bias)[tg];
    acc.x = fmaxf(acc.x + bb.x, 0.0f);
    acc.y = fmaxf(acc.y + bb.y, 0.0f);
    acc.z = fmaxf(acc.z + bb.z, 0.0f);
    acc.w = fmaxf(acc.w + bb.w, 0.0f);
    unsigned jb = (unsigned)node * 256u + (unsigned)tg * 4u;
    acc.x *= drop_scale(jb + 0u, dk0, dk1);
    acc.y *= drop_scale(jb + 1u, dk0, dk1);
    acc.z *= drop_scale(jb + 2u, dk0, dk1);
    acc.w *= drop_scale(jb + 3u, dk0, dk1);
    ((float4*)o1)[(size_t)node * 64 + tg] = acc;
  } else {
    ushort_t h0 = f2bf(acc.x), h1 = f2bf(acc.y), h2 = f2bf(acc.z), h3 = f2bf(acc.w);
    ushort4 hv = make_ushort4(h0, h1, h2, h3);
    ushort4 lv = make_ushort4(f2bf(acc.x - bf2f(h0)), f2bf(acc.y - bf2f(h1)),
                              f2bf(acc.z - bf2f(h2)), f2bf(acc.w - bf2f(h3)));
    ((ushort4*)o1)[(size_t)node * 64 + tg] = hv;
    ((ushort4*)o2)[(size_t)node * 64 + tg] = lv;
  }
}

// ---------------- fused gemm1+gemm2: 32-row slabs, 512 thr, grid 313 --------
// Per block: stage A slab (32x256 hi/lo) to LDS once; per 128-col block cb:
//   8 W1 K-steps (gemm1) -> epilogue into 32x128 H1 LDS tile (bias/relu/drop/split)
//   -> 8 W2 steps (2 col-phases x 4 K-steps) accumulating acc2.
// All tiles 128x32, dbuf, 2 gll16/step, vmcnt(2). H1 never hits global.
__global__ __launch_bounds__(512) void k_gemm12(
    const ushort_t* __restrict__ Ahi, const ushort_t* __restrict__ Alo,
    const ushort_t* __restrict__ B1h, const ushort_t* __restrict__ B1l,
    const ushort_t* __restrict__ B2h, const ushort_t* __restrict__ B2l,
    const float* __restrict__ b1, const float* __restrict__ dinv,
    float* __restrict__ hw2, int M, unsigned dk0, unsigned dk1) {
  __shared__ __attribute__((aligned(16))) ushort_t sA[16384];   // 32x256 hi|lo
  __shared__ __attribute__((aligned(16))) ushort_t sBh[2][4096], sBl[2][4096];
  __shared__ __attribute__((aligned(16))) ushort_t sHh[4096], sHl[4096];  // 32x128
  const int t = threadIdx.x;
  const int lane = t & 63, wave = t >> 6;
  const int wm = wave & 1, wn = wave >> 1;
  const int quad = lane >> 4, l16 = lane & 15;
  const int row0 = blockIdx.x * 32;
  const int skc = (((t & 3) ^ ((t >> 3) & 3)) * 8);  // staging source swizzle
  const int qx8 = (quad ^ ((l16 >> 1) & 3)) * 8;     // B-frag read swizzle
  const int rs = t >> 2;                              // staging row 0..127

  // prologue: A slab (hi+lo, chunk-XOR swizzled via source) + first W1 tile
  {
    int ch = t & 31;
    int r0a = t >> 5;  // 0..15
#pragma unroll
    for (int seg = 0; seg < 2; ++seg) {
      int row = seg * 16 + r0a;
      int ga = min(row0 + row, M - 1);
      int sc = (ch ^ (row & 7)) * 8;
      gll16(Ahi + (size_t)ga * 256 + sc, &sA[seg * 4096 + t * 8]);
      gll16(Alo + (size_t)ga * 256 + sc, &sA[8192 + seg * 4096 + t * 8]);
    }
  }
#define STG_W1(c, cb, kk8) {                                                  \
    gll16(B1h + ((size_t)(cb) * 128 + rs) * 256 + (kk8) * 32 + skc,           \
          &sBh[c][t * 8]);                                                    \
    gll16(B1l + ((size_t)(cb) * 128 + rs) * 256 + (kk8) * 32 + skc,           \
          &sBl[c][t * 8]); }
#define STG_W2(c, ph, cb, ks2) {                                              \
    gll16(B2h + ((size_t)(ph) * 128 + rs) * 512 + (cb) * 128 + (ks2) * 32 + skc, \
          &sBh[c][t * 8]);                                                    \
    gll16(B2l + ((size_t)(ph) * 128 + rs) * 512 + (cb) * 128 + (ks2) * 32 + skc, \
          &sBl[c][t * 8]); }

  STG_W1(0, 0, 0)
  asm volatile("s_waitcnt vmcnt(0)\n\ts_barrier" ::: "memory");

  floatx4 acc2[4] = {};
  int c = 0;
  const int rA = wm * 16 + l16;
  for (int cb = 0; cb < 4; ++cb) {
    floatx4 acc1[2] = {};
    // ---- gemm1: 8 K-steps over K=256 ----
    for (int kk8 = 0; kk8 < 8; ++kk8) {
      if (kk8 < 7) { STG_W1(c ^ 1, cb, kk8 + 1) }
      else { STG_W2(c ^ 1, 0, cb, 0) }
      asm volatile("s_waitcnt vmcnt(2)\n\ts_barrier" ::: "memory");
      const int offA = rA * 256 + (((kk8 * 4 + quad) ^ (rA & 7)) * 8);
      bf16x8 ah = *(const bf16x8*)&sA[offA];
      bf16x8 al = *(const bf16x8*)&sA[8192 + offA];
#pragma unroll
      for (int j = 0; j < 2; ++j) {
        const int offB = (wn * 32 + j * 16 + l16) * 32 + qx8;
        bf16x8 bh = *(const bf16x8*)&sBh[c][offB];
        bf16x8 bl = *(const bf16x8*)&sBl[c][offB];
        acc1[j] = __builtin_amdgcn_mfma_f32_16x16x32_bf16(ah, bh, acc1[j], 0, 0, 0);
        acc1[j] = __builtin_amdgcn_mfma_f32_16x16x32_bf16(ah, bl, acc1[j], 0, 0, 0);
        acc1[j] = __builtin_amdgcn_mfma_f32_16x16x32_bf16(al, bh, acc1[j], 0, 0, 0);
      }
      asm volatile("s_barrier" ::: "memory");
      c ^= 1;
    }
    // ---- epilogue: H1 tile -> sH (bias, relu, dropout, bf16 hi/lo split) ----
#pragma unroll
    for (int j = 0; j < 2; ++j) {
      int kc = wn * 32 + j * 16 + l16;     // col within tile 0..127
      int gc = cb * 128 + kc;              // H1 col 0..511
      float bb = b1[gc];
#pragma unroll
      for (int reg = 0; reg < 4; ++reg) {
        int row = wm * 16 + quad * 4 + reg;
        float v = acc1[j][reg] + bb;
        v = fmaxf(v, 0.0f);
        v *= drop_scale((unsigned)(row0 + row) * 512u + (unsigned)gc, dk0, dk1);
        ushort_t h = f2bf(v);
        int idx = row * 128 + (((kc >> 3) ^ (row & 7)) * 8) + (kc & 7);
        sHh[idx] = h;
        sHl[idx] = f2bf(v - bf2f(h));
      }
    }
    asm volatile("s_waitcnt lgkmcnt(0)\n\ts_barrier" ::: "memory");
    // ---- gemm2 partial: 2 col-phases x 4 K-steps over this cb's 128 K ----
#pragma unroll
    for (int s2 = 0; s2 < 8; ++s2) {
      const int ph = s2 >> 2, ks2 = s2 & 3;
      if (s2 < 7) { STG_W2(c ^ 1, (s2 + 1) >> 2, cb, (s2 + 1) & 3) }
      else if (cb < 3) { STG_W1(c ^ 1, cb + 1, 0) }
      if (s2 < 7 || cb < 3) {
        asm volatile("s_waitcnt vmcnt(2)\n\ts_barrier" ::: "memory");
      } else {
        asm volatile("s_waitcnt vmcnt(0)\n\ts_barrier" ::: "memory");
      }
      const int offA = rA * 128 + (((ks2 * 4 + quad) ^ (rA & 7)) * 8);
      bf16x8 ah = *(const bf16x8*)&sHh[offA];
      bf16x8 al = *(const bf16x8*)&sHl[offA];
#pragma unroll
      for (int j = 0; j < 2; ++j) {
        const int offB = (wn * 32 + j * 16 + l16) * 32 + qx8;
        bf16x8 bh = *(const bf16x8*)&sBh[c][offB];
        bf16x8 bl = *(const bf16x8*)&sBl[c][offB];
        acc2[ph * 2 + j] = __builtin_amdgcn_mfma_f32_16x16x32_bf16(ah, bh, acc2[ph * 2 + j], 0, 0, 0);
        acc2[ph * 2 + j] = __builtin_amdgcn_mfma_f32_16x16x32_bf16(ah, bl, acc2[ph * 2 + j], 0, 0, 0);
        acc2[ph * 2 + j] = __builtin_amdgcn_mfma_f32_16x16x32_bf16(al, bh, acc2[ph * 2 + j], 0, 0, 0);
      }
      asm volatile("s_barrier" ::: "memory");
      c ^= 1;
    }
  }
#undef STG_W1
#undef STG_W2
  // ---- final epilogue: hw2 = acc2 * dinv[row] (row-prescale for gather2) ----
#pragma unroll
  for (int ph = 0; ph < 2; ++ph) {
#pragma unroll
    for (int j = 0; j < 2; ++j) {
      int gc = ph * 128 + wn * 32 + j * 16 + l16;
#pragma unroll
      for (int reg = 0; reg < 4; ++reg) {
        int gr = row0 + wm * 16 + quad * 4 + reg;
        if (gr < M) hw2[(size_t)gr * 256 + gc] = acc2[ph * 2 + j][reg] * dinv[gr];
      }
    }
  }
}

extern "C" void kernel_launch(void* const* d_in, const int* in_sizes, int n_in,
                              void* d_out, int out_size, void* d_ws, size_t ws_size,
                              hipStream_t stream) {
  const float* x  = (const float*)d_in[0];
  const void*  ei = d_in[1];
  const float* W1 = (const float*)d_in[2];
  const float* b1 = (const float*)d_in[3];
  const float* W2 = (const float*)d_in[4];
  const float* b2 = (const float*)d_in[5];
  float* out = (float*)d_out;

  const int N = in_sizes[0] / C_IN;   // 10000
  const int E = in_sizes[1] / 2;      // 160000
  const int NB = (N + 255) / 256;     // 40

  unsigned a0 = 0u, a1 = 0u, b0 = 0u, b1k = 1u;
  tf_rounds(a0, a1, 0u, 42u);   // dk1
  tf_rounds(b0, b1k, 0u, 42u);  // dk2

  uintptr_t base = (uintptr_t)d_ws;
  unsigned*  flag   = (unsigned*)base;
  int*       cnt    = (int*)(base + 16 * 1024);
  int*       roff   = (int*)(base + 64 * 1024);
  int*       cursor = (int*)(base + 128 * 1024);
  float*     dinv   = (float*)(base + 192 * 1024);
  int*       csr    = (int*)(base + 2u * 1024 * 1024);
  ushort_t*  Ahi    = (ushort_t*)(base + 4u  * 1024 * 1024);
  ushort_t*  Alo    = (ushort_t*)(base + 10u * 1024 * 1024);
  float*     hw2    = (float*)(base + 38u * 1024 * 1024);
  ushort_t*  W1thi  = (ushort_t*)(base + 49u * 1024 * 1024);
  ushort_t*  W1tlo  = (ushort_t*)(base + 49u * 1024 * 1024 + 512 * 1024);
  ushort_t*  W2thi  = (ushort_t*)(base + 50u * 1024 * 1024);
  ushort_t*  W2tlo  = (ushort_t*)(base + 50u * 1024 * 1024 + 512 * 1024);

  dim3 b256(256);
  const int WCB = (C_IN * C_HID + C_HID * C_OUT + 255) / 256;

  // 1. fused setup: zero cnt | detect | weight convert
  k_setup<<<dim3(NB + 1 + WCB), b256, 0, stream>>>((const unsigned*)ei, flag, cnt,
                                                   N, NB, W1, W2,
                                                   W1thi, W1tlo, W2thi, W2tlo);
  // 2. degree histogram
  k_hist<<<dim3((E + 255) / 256), b256, 0, stream>>>(ei, flag, cnt, E);
  // 3. single-block scan
  k_scan<<<dim3(1), dim3(1024), 0, stream>>>(cnt, roff, cursor, dinv, N, E);
  // 4. CSR scatter
  k_scatter<<<dim3((E + 255) / 256), b256, 0, stream>>>(ei, flag, cursor, csr, E);
  // 5. layer-1 aggregate (full-TLP gather) -> bf16 split A
  k_gather4<0, 0><<<dim3(N / 4), b256, 0, stream>>>(roff, csr, dinv, x, nullptr,
                                                    Ahi, Alo, 0u, 0u);
  // 6. fused gemm1+gemm2 -> hw2 (row-prescaled); H1 never leaves LDS
  k_gemm12<<<dim3((N + 31) / 32), dim3(512), 0, stream>>>(
      Ahi, Alo, W1thi, W1tlo, W2thi, W2tlo, b1, dinv, hw2, N, a0, a1);
  // 7. out = drop(relu(dd * (sum hw2'[nbrs] + hw2'[self]) + b2))
  k_gather4<1, 1><<<dim3(N / 4), b256, 0, stream>>>(roff, csr, dinv, hw2, b2,
                                                    out, nullptr, b0, b1k);
}